// Round 13
// baseline (80.321 us; speedup 1.0000x reference)
//
#include <hip/hip_runtime.h>
#include <hip/hip_bf16.h>

#define D_ 64
#define HW_ 4096
#define K_ 1024
#define NPTS_ 65536
#define QOUT_ 4194304      // B*D*H*W, offset of idx region in d_out
#define DELTA 0.006f       // ambiguity margin; worst-case bf16-split diff ~2e-3
#define INF_ 3.4e38f

typedef short bf16x8 __attribute__((ext_vector_type(8)));
typedef float f32x4 __attribute__((ext_vector_type(4)));

__device__ __forceinline__ void gload_lds16(const float* g, float* l) {
    __builtin_amdgcn_global_load_lds((const __attribute__((address_space(1))) void*)g,
                                     (__attribute__((address_space(3))) void*)l, 16, 0, 0);
}
__device__ __forceinline__ void gload_lds4(const float* g, float* l) {
    __builtin_amdgcn_global_load_lds((const __attribute__((address_space(1))) void*)g,
                                     (__attribute__((address_space(3))) void*)l, 4, 0, 0);
}

// ---- pack kernel: cnorm + bf16 hi/lo split of (-2*cb) in MFMA-fragment order ----
// P layout (shorts): [gch(64)][ks(2)][lvl(2)][lane(64)][8]
//   code j = gch*16 + (l&15), dims d = ks*32 + (l>>4)*8 + i
__global__ __launch_bounds__(256) void vq_pack(const float* __restrict__ cb,
                                               float* __restrict__ cnorm,
                                               short* __restrict__ P) {
    const int t = blockIdx.x * 256 + threadIdx.x;   // 0..4095
    const int gch = t >> 6, l = t & 63;
    const int j  = gch * 16 + (l & 15);
    const int dg = l >> 4;
#pragma unroll
    for (int s = 0; s < 2; ++s) {
        const float* src = cb + j * D_ + s * 32 + dg * 8;
        short hb[8], lb[8];
#pragma unroll
        for (int i = 0; i < 8; ++i) {
            const float v = -2.f * src[i];
            __hip_bfloat16 h = __float2bfloat16(v);
            hb[i] = *(const short*)&h;
            const float r = v - __bfloat162float(h);
            __hip_bfloat16 lo = __float2bfloat16(r);
            lb[i] = *(const short*)&lo;
        }
        short* dh = P + ((size_t)((gch * 2 + s) * 2 + 0) * 64 + l) * 8;
        short* dl = P + ((size_t)((gch * 2 + s) * 2 + 1) * 64 + l) * 8;
#pragma unroll
        for (int i = 0; i < 8; ++i) { dh[i] = hb[i]; dl[i] = lb[i]; }
    }
    if (t < K_) {
        const float4* r = (const float4*)(cb + (size_t)t * D_);
        float s0 = 0.f, s1 = 0.f, s2 = 0.f, s3 = 0.f;
#pragma unroll
        for (int i = 0; i < 16; ++i) {
            float4 v = r[i];
            s0 = fmaf(v.x, v.x, s0); s1 = fmaf(v.y, v.y, s1);
            s2 = fmaf(v.z, v.z, s2); s3 = fmaf(v.w, v.w, s3);
        }
        cnorm[t] = (s0 + s1) + (s2 + s3);
    }
}

// ---- main: full-K streaming MFMA argmin with in-block K-split ----
// 1024 blocks x 512 thr (8 waves), 64 pts/block. Wave w = (tile w&3, kgroup
// w>>2); kgroups split each 64-code chunk -> wave scans 512 codes. 8192 waves
// = 8 waves/SIMD (2x R12's TLP); 16 barriers (half). (m1,m2,i1) merge across
// kgroups via LDS (disjoint code sets, lexicographic -> exact np.argmin).
// Spill tripwire: WRITE_SIZE must stay ~0.3 MB.
__global__ __launch_bounds__(512, 4) void vq_main(const float* __restrict__ x,
                                                  const float* __restrict__ cnorm_g,
                                                  const short* __restrict__ P,
                                                  float* __restrict__ out) {
    __shared__ short cbuf[2][8192];   // 2 x 16 KB: 64 codes per buffer
    __shared__ float cnt[K_];         // 4 KB
    __shared__ float gm1[2][64], gm2[2][64];
    __shared__ int   gi1[2][64];

    const int tid  = threadIdx.x;
    const int lane = tid & 63;
    const int wid  = tid >> 6;        // 0..7
    const int tile = wid & 3;         // which 16-pt tile
    const int kg   = wid >> 2;        // code half: 0 or 1
    const int pg   = blockIdx.x;      // 0..1023
    const int bb   = pg >> 6;
    const int hw0  = (pg & 63) << 6;

    const float* Pf = (const float*)P;

    // stage cnorm (4 KB) + chunk 0 (16 KB)
    gload_lds4(cnorm_g + wid * 64 + lane, cnt + wid * 64);
    gload_lds4(cnorm_g + 512 + wid * 64 + lane, cnt + 512 + wid * 64);
#pragma unroll
    for (int r = 0; r < 2; ++r)
        gload_lds16(Pf + r * 2048 + wid * 256 + lane * 4,
                    (float*)cbuf[0] + r * 2048 + wid * 256);

    // load + split x fragment: wave owns 16 points (both kgroups of a tile
    // load the same x -- duplicated, small). lane holds point (l&15).
    bf16x8 ah[2], al[2];
    {
        const float* xb = x + (size_t)bb * (D_ * HW_) + hw0;
        const int p_l = tile * 16 + (lane & 15);
#pragma unroll
        for (int s = 0; s < 2; ++s) {
            const int d0 = s * 32 + (lane >> 4) * 8;
#pragma unroll
            for (int i = 0; i < 8; ++i) {
                const float v = xb[(size_t)(d0 + i) * HW_ + p_l];
                __hip_bfloat16 h = __float2bfloat16(v);
                ah[s][i] = *(const short*)&h;
                const float r = v - __bfloat162float(h);
                __hip_bfloat16 lo = __float2bfloat16(r);
                al[s][i] = *(const short*)&lo;
            }
        }
    }
    asm volatile("s_waitcnt vmcnt(0)" ::: "memory");
    __syncthreads();

    float m1[4], m2[4];
    int   i1[4];
#pragma unroll
    for (int q = 0; q < 4; ++q) { m1[q] = INF_; m2[q] = INF_; i1[q] = 0; }

    int cur = 0;
#pragma unroll 1
    for (int c = 0; c < 16; ++c) {
        // prefetch next 64-code chunk (lands under this chunk's compute)
        if (c + 1 < 16) {
            const float* src = Pf + (size_t)(c + 1) * 4096;
            float* dst = (float*)cbuf[cur ^ 1];
#pragma unroll
            for (int r = 0; r < 2; ++r)
                gload_lds16(src + r * 2048 + wid * 256 + lane * 4,
                            dst + r * 2048 + wid * 256);
        }
        const bf16x8* fr = (const bf16x8*)cbuf[cur];
#pragma unroll
        for (int u = 0; u < 2; ++u) {
            const int gl = kg * 2 + u;             // 16-code group within chunk
            const int kc = c * 64 + gl * 16 + (lane & 15);
            const float cn = cnt[kc];
            bf16x8 bh0 = fr[(gl * 4 + 0) * 64 + lane];
            bf16x8 bl0 = fr[(gl * 4 + 1) * 64 + lane];
            bf16x8 bh1 = fr[(gl * 4 + 2) * 64 + lane];
            bf16x8 bl1 = fr[(gl * 4 + 3) * 64 + lane];
            f32x4 aa = {0.f, 0.f, 0.f, 0.f};   // s=0 terms (3-deep chain)
            f32x4 ab = {0.f, 0.f, 0.f, 0.f};   // s=1 terms (3-deep chain)
            aa = __builtin_amdgcn_mfma_f32_16x16x32_bf16(ah[0], bh0, aa, 0, 0, 0);
            ab = __builtin_amdgcn_mfma_f32_16x16x32_bf16(ah[1], bh1, ab, 0, 0, 0);
            aa = __builtin_amdgcn_mfma_f32_16x16x32_bf16(al[0], bh0, aa, 0, 0, 0);
            ab = __builtin_amdgcn_mfma_f32_16x16x32_bf16(al[1], bh1, ab, 0, 0, 0);
            aa = __builtin_amdgcn_mfma_f32_16x16x32_bf16(ah[0], bl0, aa, 0, 0, 0);
            ab = __builtin_amdgcn_mfma_f32_16x16x32_bf16(ah[1], bl1, ab, 0, 0, 0);
#pragma unroll
            for (int r = 0; r < 4; ++r) {
                const float d2 = cn + (aa[r] + ab[r]);
                const bool lt = d2 < m1[r];
                m2[r] = fminf(m2[r], fmaxf(m1[r], d2));  // min(m2, loser of (m1,d2))
                m1[r] = fminf(m1[r], d2);
                i1[r] = lt ? kc : i1[r];
            }
        }
        __syncthreads();   // prefetch complete + all waves done reading cur
        cur ^= 1;
    }

    // cross-lane (m1,i1,m2) reduce over the 16 lanes sharing (lane>>4),
    // deposit per-kgroup candidates in LDS
#pragma unroll
    for (int q = 0; q < 4; ++q) {
        float a1 = m1[q], a2 = m2[q];
        int   ai = i1[q];
#pragma unroll
        for (int m = 1; m < 16; m <<= 1) {
            const float o1 = __shfl_xor(a1, m);
            const int   oi = __shfl_xor(ai, m);
            const float o2 = __shfl_xor(a2, m);
            const float nm2 = fminf(fminf(a2, o2), fmaxf(a1, o1));
            if (o1 < a1 || (o1 == a1 && oi < ai)) { a1 = o1; ai = oi; }
            a2 = nm2;
        }
        if ((lane & 15) == 0) {
            const int pt = tile * 16 + 4 * (lane >> 4) + q;
            gm1[kg][pt] = a1; gm2[kg][pt] = a2; gi1[kg][pt] = ai;
        }
    }
    __syncthreads();

    // merge the two kgroups (disjoint code sets; lexicographic (d2, idx)) and
    // write FINAL idx with ambiguity flag in the sign.
    if (tid < 64) {
        const float a1 = gm1[0][tid], a2 = gm2[0][tid];
        const int   ai = gi1[0][tid];
        const float b1 = gm1[1][tid], b2 = gm2[1][tid];
        const int   bi = gi1[1][tid];
        float f1, f2; int fi;
        if (b1 < a1 || (b1 == a1 && bi < ai)) { f1 = b1; fi = bi; f2 = fminf(b2, a1); }
        else                                  { f1 = a1; fi = ai; f2 = fminf(a2, b1); }
        const bool amb = (f2 - f1 <= DELTA);
        out[(size_t)QOUT_ + pg * 64 + tid] = amb ? -(float)(fi + 1) : (float)fi;
    }
}

// ---- resolve: decode flagged idx, rare exact rescan, rewrite clean idx,
// gather into [d][pt] LDS tile, float4 coalesced quantized write.
__global__ __launch_bounds__(256) void vq_resolve(const float* __restrict__ x,
                                                  const float* __restrict__ cb,
                                                  const float* __restrict__ cnorm_g,
                                                  float* __restrict__ out) {
    __shared__ float tile[64 * 68];    // 17.4 KB, [d][pt] padded to 68
    __shared__ int res_idx[64];
    __shared__ int flist[64];
    __shared__ int fcnt;

    const int tid  = threadIdx.x;
    const int lane = tid & 63;
    const int wid  = tid >> 6;
    const int qg   = blockIdx.x;       // 0..1023
    const int bb   = qg >> 6;
    const int col0 = (qg & 63) << 6;   // hw of point 0

    if (tid == 0) fcnt = 0;
    __syncthreads();

    // decode idx + flag (sign-encoded by vq_main)
    if (tid < 64) {
        const float v = out[(size_t)QOUT_ + qg * 64 + tid];
        const bool fl = v < 0.f;
        res_idx[tid] = fl ? (int)(-v) - 1 : (int)v;
        if (fl) { const int p = atomicAdd(&fcnt, 1); flist[p] = tid; }
    }
    __syncthreads();

    // exact fp32 rescan for ambiguous points (expected ~0.05/block).
    const int nf = fcnt;
    for (int i = wid; i < nf; i += 4) {
        const int pt = flist[i];
        const float* xr = x + (size_t)bb * (D_ * HW_) + col0 + pt;
        float xv[D_];
#pragma unroll
        for (int d = 0; d < D_; ++d) xv[d] = xr[(size_t)d * HW_];   // wave-uniform
        float b1 = INF_; int bi = 0;
        for (int c = 0; c < 16; ++c) {
            const int row = lane * 16 + c;
            const float4* cr = (const float4*)(cb + (size_t)row * D_);
            float a0 = 0.f, a1 = 0.f, a2 = 0.f, a3 = 0.f;
#pragma unroll
            for (int g = 0; g < 16; ++g) {
                const float4 cf = cr[g];
                a0 = fmaf(xv[4 * g + 0], cf.x, a0);
                a1 = fmaf(xv[4 * g + 1], cf.y, a1);
                a2 = fmaf(xv[4 * g + 2], cf.z, a2);
                a3 = fmaf(xv[4 * g + 3], cf.w, a3);
            }
            const float dot = (a0 + a1) + (a2 + a3);
            const float d2 = fmaf(-2.f, dot, cnorm_g[row]);
            if (d2 < b1) { b1 = d2; bi = row; }
        }
#pragma unroll
        for (int m = 1; m < 64; m <<= 1) {
            const float o1 = __shfl_xor(b1, m);
            const int   oi = __shfl_xor(bi, m);
            if (o1 < b1 || (o1 == b1 && oi < bi)) { b1 = o1; bi = oi; }
        }
        if (lane == 0) res_idx[pt] = bi;
    }
    __syncthreads();

    // clean idx output (float; exact for values <= 1023)
    if (tid < 64) out[(size_t)QOUT_ + qg * 64 + tid] = (float)res_idx[tid];

    // Phase A: gather winning rows (lanes span d -> full 256B rows), store
    // transposed into [d][pt] tile
#pragma unroll
    for (int pass = 0; pass < 4; ++pass) {
        const int pt = pass * 16 + (tid >> 4);
        const int dq = tid & 15;
        const float4 v = *(const float4*)(cb + (size_t)res_idx[pt] * D_ + dq * 4);
        tile[(dq * 4 + 0) * 68 + pt] = v.x;
        tile[(dq * 4 + 1) * 68 + pt] = v.y;
        tile[(dq * 4 + 2) * 68 + pt] = v.z;
        tile[(dq * 4 + 3) * 68 + pt] = v.w;
    }
    __syncthreads();

    // Phase B: float4 stores; 16 lanes x 16 B = 256 B contiguous per d
    float* ob = out + (size_t)bb * (D_ * HW_) + col0;
#pragma unroll
    for (int i = 0; i < 4; ++i) {
        const int g = tid & 15;
        const int d = (tid >> 4) + i * 16;
        const float4 q = *(const float4*)&tile[d * 68 + g * 4];
        *(float4*)(ob + (size_t)d * HW_ + g * 4) = q;
    }
}

extern "C" void kernel_launch(void* const* d_in, const int* in_sizes, int n_in,
                              void* d_out, int out_size, void* d_ws, size_t ws_size,
                              hipStream_t stream) {
    const float* x  = (const float*)d_in[0];   // (16, 64, 64, 64)
    const float* cb = (const float*)d_in[1];   // (1024, 64)
    float* out   = (float*)d_out;
    float* cnorm = (float*)d_ws;                       // 4 KB
    short* P     = (short*)((char*)d_ws + 4096);       // 256 KB packed bf16 codebook

    vq_pack<<<16, 256, 0, stream>>>(cb, cnorm, P);
    vq_main<<<NPTS_ / 64, 512, 0, stream>>>(x, cnorm, P, out);
    vq_resolve<<<NPTS_ / 64, 256, 0, stream>>>(x, cb, cnorm, out);
}

// Round 14
// 71.961 us; speedup vs baseline: 1.1162x; 1.1162x over previous
//
#include <hip/hip_runtime.h>
#include <hip/hip_bf16.h>

#define D_ 64
#define HW_ 4096
#define K_ 1024
#define NPTS_ 65536
#define QOUT_ 4194304      // B*D*H*W, offset of idx region in d_out
#define DELTA 0.006f       // ambiguity margin; worst-case bf16-split diff ~2e-3
#define INF_ 3.4e38f

typedef short bf16x8 __attribute__((ext_vector_type(8)));
typedef float f32x4 __attribute__((ext_vector_type(4)));

__device__ __forceinline__ void gload_lds16(const float* g, float* l) {
    __builtin_amdgcn_global_load_lds((const __attribute__((address_space(1))) void*)g,
                                     (__attribute__((address_space(3))) void*)l, 16, 0, 0);
}
__device__ __forceinline__ void gload_lds4(const float* g, float* l) {
    __builtin_amdgcn_global_load_lds((const __attribute__((address_space(1))) void*)g,
                                     (__attribute__((address_space(3))) void*)l, 4, 0, 0);
}

// ---- pack kernel: cnorm + bf16 hi/lo split of (-2*cb) in MFMA-fragment order ----
// P layout (shorts): [gch(64)][ks(2)][lvl(2)][lane(64)][8]
//   code j = gch*16 + (l&15), dims d = ks*32 + (l>>4)*8 + i
__global__ __launch_bounds__(256) void vq_pack(const float* __restrict__ cb,
                                               float* __restrict__ cnorm,
                                               short* __restrict__ P) {
    const int t = blockIdx.x * 256 + threadIdx.x;   // 0..4095
    const int gch = t >> 6, l = t & 63;
    const int j  = gch * 16 + (l & 15);
    const int dg = l >> 4;
#pragma unroll
    for (int s = 0; s < 2; ++s) {
        const float* src = cb + j * D_ + s * 32 + dg * 8;
        short hb[8], lb[8];
#pragma unroll
        for (int i = 0; i < 8; ++i) {
            const float v = -2.f * src[i];
            __hip_bfloat16 h = __float2bfloat16(v);
            hb[i] = *(const short*)&h;
            const float r = v - __bfloat162float(h);
            __hip_bfloat16 lo = __float2bfloat16(r);
            lb[i] = *(const short*)&lo;
        }
        short* dh = P + ((size_t)((gch * 2 + s) * 2 + 0) * 64 + l) * 8;
        short* dl = P + ((size_t)((gch * 2 + s) * 2 + 1) * 64 + l) * 8;
#pragma unroll
        for (int i = 0; i < 8; ++i) { dh[i] = hb[i]; dl[i] = lb[i]; }
    }
    if (t < K_) {
        const float4* r = (const float4*)(cb + (size_t)t * D_);
        float s0 = 0.f, s1 = 0.f, s2 = 0.f, s3 = 0.f;
#pragma unroll
        for (int i = 0; i < 16; ++i) {
            float4 v = r[i];
            s0 = fmaf(v.x, v.x, s0); s1 = fmaf(v.y, v.y, s1);
            s2 = fmaf(v.z, v.z, s2); s3 = fmaf(v.w, v.w, s3);
        }
        cnorm[t] = (s0 + s1) + (s2 + s3);
    }
}

// ---- fused main: streaming MFMA argmin + merge + rescan + quantized write ----
// 512 blocks x 512 thr (8 waves). Wave = (pgrp wid&3, kgroup wid>>2); owns 32
// points (two 16x16 A-tiles) x 512 codes -> B-fragment LDS reads halve vs
// 16pts/wave (2 MB/CU). 8 chunks of 128 codes, double-buffered (2x32KB).
// Epilogue fused in-block: kgroup merge (disjoint sets, lexicographic), rare
// exact fp32 rescan, gather + LDS transpose (aliases cbuf) + float4 stores.
// Spill tripwire: WRITE_SIZE must stay ~17 MB.
__global__ __launch_bounds__(512, 4) void vq_main(const float* __restrict__ x,
                                                  const float* __restrict__ cb,
                                                  const float* __restrict__ cnorm_g,
                                                  const short* __restrict__ P,
                                                  float* __restrict__ out) {
    __shared__ short cbuf[2][16384];   // 2 x 32 KB: 128 codes per buffer
    __shared__ float cnt[K_];          // 4 KB
    __shared__ float gm1[2][128], gm2[2][128];
    __shared__ int   gi1[2][128];
    __shared__ int   res_idx[128];
    __shared__ int   flist[128];
    __shared__ int   fcnt;

    const int tid  = threadIdx.x;
    const int lane = tid & 63;
    const int wid  = tid >> 6;        // 0..7
    const int pgp  = wid & 3;         // 32-pt group within block
    const int kg   = wid >> 2;        // code half: 0 or 1
    const int pg   = blockIdx.x;      // 0..511
    const int bb   = pg >> 5;
    const int hw0  = (pg & 31) << 7;  // 128 pts per block

    if (tid == 0) fcnt = 0;

    const float* Pf = (const float*)P;

    // stage cnorm (4 KB) + chunk 0 (32 KB)
    gload_lds4(cnorm_g + wid * 64 + lane, cnt + wid * 64);
    gload_lds4(cnorm_g + 512 + wid * 64 + lane, cnt + 512 + wid * 64);
#pragma unroll
    for (int r = 0; r < 4; ++r)
        gload_lds16(Pf + wid * 1024 + r * 256 + lane * 4,
                    (float*)cbuf[0] + wid * 1024 + r * 256);

    // load + split x fragments: wave owns 32 points (2 tiles); kgroup twins
    // duplicate the same x (small cost). lane holds point (l&15).
    bf16x8 ah[2][2], al[2][2];
    {
        const float* xb = x + (size_t)bb * (D_ * HW_) + hw0;
#pragma unroll
        for (int t = 0; t < 2; ++t) {
            const int p_l = pgp * 32 + t * 16 + (lane & 15);
#pragma unroll
            for (int s = 0; s < 2; ++s) {
                const int d0 = s * 32 + (lane >> 4) * 8;
#pragma unroll
                for (int i = 0; i < 8; ++i) {
                    const float v = xb[(size_t)(d0 + i) * HW_ + p_l];
                    __hip_bfloat16 h = __float2bfloat16(v);
                    ah[t][s][i] = *(const short*)&h;
                    const float r = v - __bfloat162float(h);
                    __hip_bfloat16 lo = __float2bfloat16(r);
                    al[t][s][i] = *(const short*)&lo;
                }
            }
        }
    }
    asm volatile("s_waitcnt vmcnt(0)" ::: "memory");
    __syncthreads();

    float m1[8], m2[8];
    int   i1[8];
#pragma unroll
    for (int q = 0; q < 8; ++q) { m1[q] = INF_; m2[q] = INF_; i1[q] = 0; }

    int cur = 0;
#pragma unroll 1
    for (int c = 0; c < 8; ++c) {
        // prefetch next 128-code chunk (lands under this chunk's compute)
        if (c + 1 < 8) {
            const float* src = Pf + (size_t)(c + 1) * 8192;
            float* dst = (float*)cbuf[cur ^ 1];
#pragma unroll
            for (int r = 0; r < 4; ++r)
                gload_lds16(src + wid * 1024 + r * 256 + lane * 4,
                            dst + wid * 1024 + r * 256);
        }
        const bf16x8* fr = (const bf16x8*)cbuf[cur];
#pragma unroll
        for (int g = 0; g < 4; ++g) {            // R10-proven window of 4
            const int gl = kg * 4 + g;           // 16-code group within chunk
            const int kc = c * 128 + gl * 16 + (lane & 15);
            const float cn = cnt[kc];
            bf16x8 bh0 = fr[(gl * 4 + 0) * 64 + lane];
            bf16x8 bl0 = fr[(gl * 4 + 1) * 64 + lane];
            bf16x8 bh1 = fr[(gl * 4 + 2) * 64 + lane];
            bf16x8 bl1 = fr[(gl * 4 + 3) * 64 + lane];
            f32x4 a0a = {0.f, 0.f, 0.f, 0.f};   // tile0, s=0 (3-deep chain)
            f32x4 a0b = {0.f, 0.f, 0.f, 0.f};   // tile0, s=1
            f32x4 a1a = {0.f, 0.f, 0.f, 0.f};   // tile1, s=0
            f32x4 a1b = {0.f, 0.f, 0.f, 0.f};   // tile1, s=1
            a0a = __builtin_amdgcn_mfma_f32_16x16x32_bf16(ah[0][0], bh0, a0a, 0, 0, 0);
            a1a = __builtin_amdgcn_mfma_f32_16x16x32_bf16(ah[1][0], bh0, a1a, 0, 0, 0);
            a0b = __builtin_amdgcn_mfma_f32_16x16x32_bf16(ah[0][1], bh1, a0b, 0, 0, 0);
            a1b = __builtin_amdgcn_mfma_f32_16x16x32_bf16(ah[1][1], bh1, a1b, 0, 0, 0);
            a0a = __builtin_amdgcn_mfma_f32_16x16x32_bf16(al[0][0], bh0, a0a, 0, 0, 0);
            a1a = __builtin_amdgcn_mfma_f32_16x16x32_bf16(al[1][0], bh0, a1a, 0, 0, 0);
            a0b = __builtin_amdgcn_mfma_f32_16x16x32_bf16(al[0][1], bh1, a0b, 0, 0, 0);
            a1b = __builtin_amdgcn_mfma_f32_16x16x32_bf16(al[1][1], bh1, a1b, 0, 0, 0);
            a0a = __builtin_amdgcn_mfma_f32_16x16x32_bf16(ah[0][0], bl0, a0a, 0, 0, 0);
            a1a = __builtin_amdgcn_mfma_f32_16x16x32_bf16(ah[1][0], bl0, a1a, 0, 0, 0);
            a0b = __builtin_amdgcn_mfma_f32_16x16x32_bf16(ah[0][1], bl1, a0b, 0, 0, 0);
            a1b = __builtin_amdgcn_mfma_f32_16x16x32_bf16(ah[1][1], bl1, a1b, 0, 0, 0);
#pragma unroll
            for (int t = 0; t < 2; ++t)
#pragma unroll
                for (int r = 0; r < 4; ++r) {
                    const int q = t * 4 + r;
                    const float d2 = cn + ((t == 0) ? (a0a[r] + a0b[r])
                                                    : (a1a[r] + a1b[r]));
                    const bool lt = d2 < m1[q];
                    m2[q] = fminf(m2[q], fmaxf(m1[q], d2));
                    m1[q] = fminf(m1[q], d2);
                    i1[q] = lt ? kc : i1[q];
                }
        }
        __syncthreads();   // prefetch landed + all waves done reading cur
        cur ^= 1;
    }

    // cross-lane (m1,i1,m2) reduce over the 16 lanes sharing (lane>>4)
#pragma unroll
    for (int q = 0; q < 8; ++q) {
        float a1 = m1[q], a2 = m2[q];
        int   ai = i1[q];
#pragma unroll
        for (int m = 1; m < 16; m <<= 1) {
            const float o1 = __shfl_xor(a1, m);
            const int   oi = __shfl_xor(ai, m);
            const float o2 = __shfl_xor(a2, m);
            const float nm2 = fminf(fminf(a2, o2), fmaxf(a1, o1));
            if (o1 < a1 || (o1 == a1 && oi < ai)) { a1 = o1; ai = oi; }
            a2 = nm2;
        }
        if ((lane & 15) == 0) {
            const int t = q >> 2, r = q & 3;
            const int pt = pgp * 32 + t * 16 + 4 * (lane >> 4) + r;
            gm1[kg][pt] = a1; gm2[kg][pt] = a2; gi1[kg][pt] = ai;
        }
    }
    __syncthreads();

    // merge the two kgroups (disjoint code sets; lexicographic (d2, idx))
    if (tid < 128) {
        const float a1 = gm1[0][tid], a2 = gm2[0][tid];
        const int   ai = gi1[0][tid];
        const float b1 = gm1[1][tid], b2 = gm2[1][tid];
        const int   bi = gi1[1][tid];
        float f1, f2; int fi;
        if (b1 < a1 || (b1 == a1 && bi < ai)) { f1 = b1; fi = bi; f2 = fminf(b2, a1); }
        else                                  { f1 = a1; fi = ai; f2 = fminf(a2, b1); }
        res_idx[tid] = fi;
        if (f2 - f1 <= DELTA) { const int p = atomicAdd(&fcnt, 1); flist[p] = tid; }
    }
    __syncthreads();

    // exact fp32 rescan for ambiguous points (expected ~0.05/block).
    const int nf = fcnt;
    for (int i = wid; i < nf; i += 8) {
        const int pt = flist[i];
        const float* xr = x + (size_t)bb * (D_ * HW_) + hw0 + pt;
        float xv[D_];
#pragma unroll
        for (int d = 0; d < D_; ++d) xv[d] = xr[(size_t)d * HW_];   // wave-uniform
        float b1 = INF_; int bi = 0;
        for (int cc = 0; cc < 16; ++cc) {
            const int row = lane * 16 + cc;
            const float4* cr = (const float4*)(cb + (size_t)row * D_);
            float a0 = 0.f, a1 = 0.f, a2 = 0.f, a3 = 0.f;
#pragma unroll
            for (int g = 0; g < 16; ++g) {
                const float4 cf = cr[g];
                a0 = fmaf(xv[4 * g + 0], cf.x, a0);
                a1 = fmaf(xv[4 * g + 1], cf.y, a1);
                a2 = fmaf(xv[4 * g + 2], cf.z, a2);
                a3 = fmaf(xv[4 * g + 3], cf.w, a3);
            }
            const float dot = (a0 + a1) + (a2 + a3);
            const float d2 = fmaf(-2.f, dot, cnorm_g[row]);
            if (d2 < b1) { b1 = d2; bi = row; }
        }
#pragma unroll
        for (int m = 1; m < 64; m <<= 1) {
            const float o1 = __shfl_xor(b1, m);
            const int   oi = __shfl_xor(bi, m);
            if (o1 < b1 || (o1 == b1 && oi < bi)) { b1 = o1; bi = oi; }
        }
        if (lane == 0) res_idx[pt] = bi;
    }
    __syncthreads();

    // idx output (float; exact for values <= 1023)
    if (tid < 128) out[(size_t)QOUT_ + pg * 128 + tid] = (float)res_idx[tid];

    // Phase A: gather winning rows (16 lanes x 16 B = full 256 B row each),
    // write transposed into [d][pt] tile aliasing cbuf (33 KB <= 64 KB).
    float* tile = (float*)&cbuf[0][0];      // [64][132]
#pragma unroll
    for (int pass = 0; pass < 4; ++pass) {
        const int pt = pass * 32 + (tid >> 4);
        const int dq = tid & 15;
        const float4 v = *(const float4*)(cb + (size_t)res_idx[pt] * D_ + dq * 4);
        tile[(dq * 4 + 0) * 132 + pt] = v.x;
        tile[(dq * 4 + 1) * 132 + pt] = v.y;
        tile[(dq * 4 + 2) * 132 + pt] = v.z;
        tile[(dq * 4 + 3) * 132 + pt] = v.w;
    }
    __syncthreads();

    // Phase B: float4 stores; per d, 128 pts x 4 B = 512 B contiguous
    float* ob = out + (size_t)bb * (D_ * HW_) + hw0;
#pragma unroll
    for (int i = 0; i < 4; ++i) {
        const int e = i * 512 + tid;
        const int d = e >> 5;
        const int g = e & 31;
        const float4 q = *(const float4*)&tile[d * 132 + g * 4];
        *(float4*)(ob + (size_t)d * HW_ + g * 4) = q;
    }
}

extern "C" void kernel_launch(void* const* d_in, const int* in_sizes, int n_in,
                              void* d_out, int out_size, void* d_ws, size_t ws_size,
                              hipStream_t stream) {
    const float* x  = (const float*)d_in[0];   // (16, 64, 64, 64)
    const float* cb = (const float*)d_in[1];   // (1024, 64)
    float* out   = (float*)d_out;
    float* cnorm = (float*)d_ws;                       // 4 KB
    short* P     = (short*)((char*)d_ws + 4096);       // 256 KB packed bf16 codebook

    vq_pack<<<16, 256, 0, stream>>>(cb, cnorm, P);
    vq_main<<<NPTS_ / 128, 512, 0, stream>>>(x, cb, cnorm, P, out);
}